// Round 1
// baseline (2700.548 us; speedup 1.0000x reference)
//
#include <hip/hip_runtime.h>

#define BB   8
#define DD   128
#define HHH  4
#define NNN  2048
#define MMM  2048
#define DH   32
#define TN   16   // score rows per attention block

// ---------------------------------------------------------------- GEMM
// C[rblk..rblk+127, n0..n0+63] for batch b.
// MODE 0: qkv proj  -> out[b][h][n][e]  (c = e*4 + h head-split transpose)
// MODE 1: plain bias -> out[b][c][n]
// MODE 2: bias + BN + ReLU, input = concat(x, msg2) along channels
// MODE 3: bias       -> out[b][c][n]   (final delta)
template<int MODE>
__global__ __launch_bounds__(256)
void gemm_k(const float* __restrict__ W, const float* __restrict__ bias,
            const float* __restrict__ X0, const float* __restrict__ X1,
            float* __restrict__ out, int K, int Mrows,
            const float* __restrict__ g1, const float* __restrict__ be1,
            const float* __restrict__ mu1, const float* __restrict__ va1)
{
  __shared__ float Wt[32][132];   // [kk][r], +4 pad keeps b128 reads spread
  __shared__ float Xl[32][64];    // [kk][n]
  const int tid = threadIdx.x;
  const int b   = blockIdx.x >> 5;          // 32 col-tiles per batch
  const int n0  = (blockIdx.x & 31) << 6;
  const int rblk = blockIdx.y << 7;
  const int tx = tid & 15, ty = tid >> 4;

  float acc[8][4];
#pragma unroll
  for (int i = 0; i < 8; ++i)
#pragma unroll
    for (int j = 0; j < 4; ++j) acc[i][j] = 0.f;

  for (int k0 = 0; k0 < K; k0 += 32) {
    // stage W tile (128 rows x 32 k) transposed into LDS
#pragma unroll
    for (int i = 0; i < 4; ++i) {
      int idx = tid + i * 256;            // 0..1023
      int r = idx >> 3, kv = (idx & 7) << 2;
      const float4 w4 = *(const float4*)&W[(size_t)(rblk + r) * K + k0 + kv];
      Wt[kv + 0][r] = w4.x; Wt[kv + 1][r] = w4.y;
      Wt[kv + 2][r] = w4.z; Wt[kv + 3][r] = w4.w;
    }
    // stage X tile (32 k x 64 n)
#pragma unroll
    for (int i = 0; i < 2; ++i) {
      int idx = tid + i * 256;            // 0..511
      int kk = idx >> 4, j4 = (idx & 15) << 2;
      int kg = k0 + kk;
      const float* src;
      if (MODE == 2)
        src = (kg < DD) ? &X0[((size_t)b * DD + kg) * NNN]
                        : &X1[((size_t)b * DD + (kg - DD)) * NNN];
      else
        src = &X0[((size_t)b * K + kg) * NNN];
      *(float4*)&Xl[kk][j4] = *(const float4*)&src[n0 + j4];
    }
    __syncthreads();
#pragma unroll
    for (int kk = 0; kk < 32; ++kk) {
      float a[8], bx[4];
      *(float4*)&a[0] = *(const float4*)&Wt[kk][ty * 8];
      *(float4*)&a[4] = *(const float4*)&Wt[kk][ty * 8 + 4];
      *(float4*)&bx[0] = *(const float4*)&Xl[kk][tx * 4];
#pragma unroll
      for (int i = 0; i < 8; ++i)
#pragma unroll
        for (int j = 0; j < 4; ++j) acc[i][j] = fmaf(a[i], bx[j], acc[i][j]);
    }
    __syncthreads();
  }

#pragma unroll
  for (int i = 0; i < 8; ++i) {
    const int r = rblk + ty * 8 + i;
    const float bv = bias[r];
    float scale = 1.f, shift = 0.f;
    if (MODE == 2) {
      const float inv = rsqrtf(va1[r] + 1e-5f);
      scale = g1[r] * inv;
      shift = be1[r] - mu1[r] * scale;
    }
#pragma unroll
    for (int j = 0; j < 4; ++j) {
      const int n = n0 + tx * 4 + j;
      float v = acc[i][j] + bv;
      if (MODE == 2) { v = fmaf(v, scale, shift); v = v > 0.f ? v : 0.f; }
      if (MODE == 0) {
        // channel c = r -> head h = r&3, per-head feature e = r>>2
        out[(((size_t)b * HHH + (r & 3)) * NNN + n) * DH + (r >> 2)] = v;
      } else {
        out[((size_t)b * Mrows + r) * NNN + n] = v;
      }
    }
  }
}

// ---------------------------------------------------------------- attention
// One block per (b, h, 16 n-rows). 256 threads = 4 waves, 4 rows per wave.
// Phase 1: fp32 scores [16][2048] into LDS (q in VGPRs, k chunks staged in LDS).
// Phase 2: per-wave exact top-32 extraction + softmax + sparse P*V.
__global__ __launch_bounds__(256)
void attn_k(const float* __restrict__ qt, const float* __restrict__ kt,
            const float* __restrict__ vt, float* __restrict__ msg)
{
  extern __shared__ char smem[];
  float* Sc = (float*)smem;                                  // [16][2048] fp32
  float (*Kl)[36] = (float(*)[36])(smem + (size_t)TN * MMM * 4); // [64][36]

  const int tid  = threadIdx.x;
  const int wave = tid >> 6, lane = tid & 63;
  const int h = blockIdx.y, b = blockIdx.z;
  const int n0 = blockIdx.x * TN;
  const size_t bh = (size_t)b * HHH + h;
  const float* kbase = kt + bh * MMM * DH;
  const float* vbase = vt + bh * MMM * DH;
  const float* qbase = qt + (bh * NNN + n0) * DH;

  // q for this wave's 4 rows, replicated across lanes (128 VGPRs)
  float4 qv[4][8];
#pragma unroll
  for (int rr = 0; rr < 4; ++rr) {
    const float4* qr = (const float4*)(qbase + (size_t)(wave * 4 + rr) * DH);
#pragma unroll
    for (int i = 0; i < 8; ++i) qv[rr][i] = qr[i];
  }

  // ---- phase 1: scores ----
  const float4* kg4 = (const float4*)kbase;   // 16384 float4 per (b,h)
  float4 pre0 = kg4[tid], pre1 = kg4[tid + 256];
  for (int c = 0; c < 32; ++c) {
    __syncthreads();                           // Kl free to overwrite
    {
      const int m0 = tid >> 3,        e0 = (tid & 7) << 2;
      const int m1 = (tid + 256) >> 3, e1 = (tid & 7) << 2;
      *(float4*)&Kl[m0][e0] = pre0;
      *(float4*)&Kl[m1][e1] = pre1;
    }
    __syncthreads();
    if (c < 31) {                              // prefetch next chunk (hides HBM/L2)
      pre0 = kg4[(c + 1) * 512 + tid];
      pre1 = kg4[(c + 1) * 512 + tid + 256];
    }
    float a0 = 0.f, a1 = 0.f, a2 = 0.f, a3 = 0.f;
#pragma unroll
    for (int i = 0; i < 8; ++i) {
      const float4 kv4 = *(const float4*)&Kl[lane][i * 4];
      a0 = fmaf(qv[0][i].x, kv4.x, a0); a0 = fmaf(qv[0][i].y, kv4.y, a0);
      a0 = fmaf(qv[0][i].z, kv4.z, a0); a0 = fmaf(qv[0][i].w, kv4.w, a0);
      a1 = fmaf(qv[1][i].x, kv4.x, a1); a1 = fmaf(qv[1][i].y, kv4.y, a1);
      a1 = fmaf(qv[1][i].z, kv4.z, a1); a1 = fmaf(qv[1][i].w, kv4.w, a1);
      a2 = fmaf(qv[2][i].x, kv4.x, a2); a2 = fmaf(qv[2][i].y, kv4.y, a2);
      a2 = fmaf(qv[2][i].z, kv4.z, a2); a2 = fmaf(qv[2][i].w, kv4.w, a2);
      a3 = fmaf(qv[3][i].x, kv4.x, a3); a3 = fmaf(qv[3][i].y, kv4.y, a3);
      a3 = fmaf(qv[3][i].z, kv4.z, a3); a3 = fmaf(qv[3][i].w, kv4.w, a3);
    }
    const float rs = 0.17677669529663687f;     // 1/sqrt(32)
    const int m = c * 64 + lane;
    Sc[(size_t)(wave * 4 + 0) * MMM + m] = a0 * rs;
    Sc[(size_t)(wave * 4 + 1) * MMM + m] = a1 * rs;
    Sc[(size_t)(wave * 4 + 2) * MMM + m] = a2 * rs;
    Sc[(size_t)(wave * 4 + 3) * MMM + m] = a3 * rs;
  }
  __syncthreads();

  // ---- phase 2: top-32 + softmax + P*V, one row at a time per wave ----
#pragma unroll 1
  for (int rr = 0; rr < 4; ++rr) {
    const int row = wave * 4 + rr;
    const int n = n0 + row;
    float s[32];
    const float* srow = &Sc[(size_t)row * MMM];
#pragma unroll
    for (int j = 0; j < 32; ++j) s[j] = srow[j * 64 + lane];

    unsigned consumed = 0u;
    float lmax = -INFINITY; int lidx = 0;
#pragma unroll
    for (int j = 0; j < 32; ++j)
      if (s[j] > lmax) { lmax = s[j]; lidx = j; }

    float selv = 0.f; int selm = 0;
#pragma unroll 1
    for (int t = 0; t < 32; ++t) {
      float mv = lmax; int mm = lidx * 64 + lane;
#pragma unroll
      for (int d = 1; d < 64; d <<= 1) {
        const float ov = __shfl_xor(mv, d);
        const int   om = __shfl_xor(mm, d);
        if (ov > mv || (ov == mv && om < mm)) { mv = ov; mm = om; }
      }
      if (lane == t) { selv = mv; selm = mm; }
      if ((mm & 63) == lane) {                 // owner: drop it, rescan
        consumed |= 1u << (mm >> 6);
        lmax = -INFINITY; lidx = 0;
#pragma unroll
        for (int j = 0; j < 32; ++j)
          if (!((consumed >> j) & 1u) && s[j] > lmax) { lmax = s[j]; lidx = j; }
      }
    }
    // softmax over the 32 selected (lane t holds t-th largest)
    const float maxv = __shfl(selv, 0);
    float p = (lane < 32) ? __expf(selv - maxv) : 0.f;
    float ps = p;
#pragma unroll
    for (int d = 1; d < 64; d <<= 1) ps += __shfl_xor(ps, d);
    const float Sv = p / ps;

    // msg[e, n] = sum_j S_j * v[m_j][e]; halves split the 32 terms
    const int e = lane & 31, half = lane >> 5;
    float acc = 0.f;
#pragma unroll
    for (int jj = 0; jj < 16; ++jj) {
      const int j = jj * 2 + half;
      const float Sj = __shfl(Sv, j);
      const int   mj = __shfl(selm, j);
      acc = fmaf(Sj, vbase[(size_t)mj * DH + e], acc);
    }
    acc += __shfl_xor(acc, 32);
    if (lane < 32)
      msg[((size_t)b * DD + (e * HHH + h)) * NNN + n] = acc;   // c = e*4 + h
  }
}

// ---------------------------------------------------------------- launch
extern "C" void kernel_launch(void* const* d_in, const int* in_sizes, int n_in,
                              void* d_out, int out_size, void* d_ws, size_t ws_size,
                              hipStream_t stream)
{
  const float* x   = (const float*)d_in[0];
  const float* src = (const float*)d_in[1];
  const float* Wq  = (const float*)d_in[2];
  const float* bq  = (const float*)d_in[3];
  const float* Wk  = (const float*)d_in[4];
  const float* bk  = (const float*)d_in[5];
  const float* Wv  = (const float*)d_in[6];
  const float* bv  = (const float*)d_in[7];
  const float* Wm  = (const float*)d_in[8];
  const float* bm  = (const float*)d_in[9];
  const float* W1  = (const float*)d_in[10];
  const float* b1  = (const float*)d_in[11];
  const float* g1  = (const float*)d_in[12];
  const float* be1 = (const float*)d_in[13];
  const float* mu1 = (const float*)d_in[14];
  const float* va1 = (const float*)d_in[15];
  const float* W2  = (const float*)d_in[16];
  const float* b2  = (const float*)d_in[17];

  float* ws = (float*)d_ws;
  const size_t SEG = 2097152;           // 8 MB in floats
  float* q_t  = ws;                     // [B][H][N][32]
  float* k_t  = ws + SEG;               // [B][H][M][32]
  float* v_t  = ws + 2 * SEG;           // [B][H][M][32]
  float* msg  = ws + 3 * SEG;           // [B][128][N]
  float* msg2 = ws;                     // reuse q_t region
  float* z    = ws + SEG;               // [B][256][N], reuse k_t+v_t

  const dim3 blk(256);
  const dim3 g128(256, 1), g256(256, 2);

  gemm_k<0><<<g128, blk, 0, stream>>>(Wq, bq, x,   nullptr, q_t, 128, 128,
                                      nullptr, nullptr, nullptr, nullptr);
  gemm_k<0><<<g128, blk, 0, stream>>>(Wk, bk, src, nullptr, k_t, 128, 128,
                                      nullptr, nullptr, nullptr, nullptr);
  gemm_k<0><<<g128, blk, 0, stream>>>(Wv, bv, src, nullptr, v_t, 128, 128,
                                      nullptr, nullptr, nullptr, nullptr);

  const size_t smem = (size_t)TN * MMM * 4 + 64 * 36 * 4;   // 140288 B
  hipFuncSetAttribute(reinterpret_cast<const void*>(attn_k),
                      hipFuncAttributeMaxDynamicSharedMemorySize, (int)smem);
  const dim3 ga(NNN / TN, HHH, BB);
  attn_k<<<ga, blk, smem, stream>>>(q_t, k_t, v_t, msg);

  gemm_k<1><<<g128, blk, 0, stream>>>(Wm, bm, msg, nullptr, msg2, 128, 128,
                                      nullptr, nullptr, nullptr, nullptr);
  gemm_k<2><<<g256, blk, 0, stream>>>(W1, b1, x, msg2, z, 256, 256,
                                      g1, be1, mu1, va1);
  gemm_k<3><<<g128, blk, 0, stream>>>(W2, b2, z, nullptr, (float*)d_out, 256, 128,
                                      nullptr, nullptr, nullptr, nullptr);
}

// Round 2
// 599.391 us; speedup vs baseline: 4.5055x; 4.5055x over previous
//
#include <hip/hip_runtime.h>

#define BB   8
#define DD   128
#define HHH  4
#define NNN  2048
#define MMM  2048
#define DH   32
#define TN   16   // score rows per attention block

// ---------------------------------------------------------------- GEMM
// C[rblk..rblk+127, n0..n0+63] for batch b.
// MODE 0: qkv proj  -> out[b][h][n][e]  (c = e*4 + h head-split transpose)
// MODE 1: plain bias -> out[b][c][n]
// MODE 2: bias + BN + ReLU, input = concat(x, msg2) along channels
// MODE 3: bias       -> out[b][c][n]   (final delta)
template<int MODE>
__global__ __launch_bounds__(256)
void gemm_k(const float* __restrict__ W, const float* __restrict__ bias,
            const float* __restrict__ X0, const float* __restrict__ X1,
            float* __restrict__ out, int K, int Mrows,
            const float* __restrict__ g1, const float* __restrict__ be1,
            const float* __restrict__ mu1, const float* __restrict__ va1)
{
  __shared__ float Wt[32][132];
  __shared__ float Xl[32][64];
  const int tid = threadIdx.x;
  const int b   = blockIdx.x >> 5;
  const int n0  = (blockIdx.x & 31) << 6;
  const int rblk = blockIdx.y << 7;
  const int tx = tid & 15, ty = tid >> 4;

  float acc[8][4];
#pragma unroll
  for (int i = 0; i < 8; ++i)
#pragma unroll
    for (int j = 0; j < 4; ++j) acc[i][j] = 0.f;

  for (int k0 = 0; k0 < K; k0 += 32) {
#pragma unroll
    for (int i = 0; i < 4; ++i) {
      int idx = tid + i * 256;
      int r = idx >> 3, kv = (idx & 7) << 2;
      const float4 w4 = *(const float4*)&W[(size_t)(rblk + r) * K + k0 + kv];
      Wt[kv + 0][r] = w4.x; Wt[kv + 1][r] = w4.y;
      Wt[kv + 2][r] = w4.z; Wt[kv + 3][r] = w4.w;
    }
#pragma unroll
    for (int i = 0; i < 2; ++i) {
      int idx = tid + i * 256;
      int kk = idx >> 4, j4 = (idx & 15) << 2;
      int kg = k0 + kk;
      const float* src;
      if (MODE == 2)
        src = (kg < DD) ? &X0[((size_t)b * DD + kg) * NNN]
                        : &X1[((size_t)b * DD + (kg - DD)) * NNN];
      else
        src = &X0[((size_t)b * K + kg) * NNN];
      *(float4*)&Xl[kk][j4] = *(const float4*)&src[n0 + j4];
    }
    __syncthreads();
#pragma unroll
    for (int kk = 0; kk < 32; ++kk) {
      float a[8], bx[4];
      *(float4*)&a[0] = *(const float4*)&Wt[kk][ty * 8];
      *(float4*)&a[4] = *(const float4*)&Wt[kk][ty * 8 + 4];
      *(float4*)&bx[0] = *(const float4*)&Xl[kk][tx * 4];
#pragma unroll
      for (int i = 0; i < 8; ++i)
#pragma unroll
        for (int j = 0; j < 4; ++j) acc[i][j] = fmaf(a[i], bx[j], acc[i][j]);
    }
    __syncthreads();
  }

#pragma unroll
  for (int i = 0; i < 8; ++i) {
    const int r = rblk + ty * 8 + i;
    const float bv = bias[r];
    float scale = 1.f, shift = 0.f;
    if (MODE == 2) {
      const float inv = rsqrtf(va1[r] + 1e-5f);
      scale = g1[r] * inv;
      shift = be1[r] - mu1[r] * scale;
    }
#pragma unroll
    for (int j = 0; j < 4; ++j) {
      const int n = n0 + tx * 4 + j;
      float v = acc[i][j] + bv;
      if (MODE == 2) { v = fmaf(v, scale, shift); v = v > 0.f ? v : 0.f; }
      if (MODE == 0) {
        out[(((size_t)b * HHH + (r & 3)) * NNN + n) * DH + (r >> 2)] = v;
      } else {
        out[((size_t)b * Mrows + r) * NNN + n] = v;
      }
    }
  }
}

// ---------------------------------------------------------------- helpers
__device__ __forceinline__ int dpp_scan_i32(int v) {
  // inclusive prefix-sum across 64 lanes (classic GCN row_shr/row_bcast idiom)
  v += __builtin_amdgcn_update_dpp(0, v, 0x111, 0xF, 0xF, true); // row_shr:1
  v += __builtin_amdgcn_update_dpp(0, v, 0x112, 0xF, 0xF, true); // row_shr:2
  v += __builtin_amdgcn_update_dpp(0, v, 0x114, 0xF, 0xF, true); // row_shr:4
  v += __builtin_amdgcn_update_dpp(0, v, 0x118, 0xF, 0xF, true); // row_shr:8
  v += __builtin_amdgcn_update_dpp(0, v, 0x142, 0xA, 0xF, true); // row_bcast:15
  v += __builtin_amdgcn_update_dpp(0, v, 0x143, 0xC, 0xF, true); // row_bcast:31
  return v;
}

__device__ __forceinline__ unsigned ordkey(float f) {
  unsigned b = __float_as_uint(f);
  return (b & 0x80000000u) ? ~b : (b | 0x80000000u);
}

__device__ __forceinline__ void transpose32(unsigned (&A)[32]) {
  unsigned m = 0x0000FFFFu;
#pragma unroll
  for (int j = 16; j != 0; j = j >> 1, m = m ^ (m << j)) {
#pragma unroll
    for (int k = 0; k < 32; ++k) {
      if (!(k & j)) {
        unsigned t = (A[k] ^ (A[k + j] >> j)) & m;
        A[k]     ^= t;
        A[k + j] ^= t << j;
      }
    }
  }
}

// ---------------------------------------------------------------- attention
// Phase 1: fp32 scores [16][2048] into LDS (unchanged).
// Phase 2: exact top-32 via per-lane bit-transpose + radix select over the
// order-preserving uint key; wave counts via DPP scan (VALU, not bpermute).
__global__ __launch_bounds__(256, 1)
void attn_k(const float* __restrict__ qt, const float* __restrict__ kt,
            const float* __restrict__ vt, float* __restrict__ msg)
{
  extern __shared__ char smem[];
  float* Sc = (float*)smem;                                      // [16][2048]
  float (*Kl)[36] = (float(*)[36])(smem + (size_t)TN * MMM * 4); // [64][36]

  const int tid  = threadIdx.x;
  const int wave = tid >> 6, lane = tid & 63;
  const int h = blockIdx.y, b = blockIdx.z;
  const int n0 = blockIdx.x * TN;
  const size_t bh = (size_t)b * HHH + h;
  const float* kbase = kt + bh * MMM * DH;
  const float* vbase = vt + bh * MMM * DH;
  const float* qbase = qt + (bh * NNN + n0) * DH;

  float4 qv[4][8];
#pragma unroll
  for (int rr = 0; rr < 4; ++rr) {
    const float4* qr = (const float4*)(qbase + (size_t)(wave * 4 + rr) * DH);
#pragma unroll
    for (int i = 0; i < 8; ++i) qv[rr][i] = qr[i];
  }

  // ---- phase 1: scores ----
  const float4* kg4 = (const float4*)kbase;
  float4 pre0 = kg4[tid], pre1 = kg4[tid + 256];
  for (int c = 0; c < 32; ++c) {
    __syncthreads();
    {
      const int m0 = tid >> 3,         e0 = (tid & 7) << 2;
      const int m1 = (tid + 256) >> 3, e1 = (tid & 7) << 2;
      *(float4*)&Kl[m0][e0] = pre0;
      *(float4*)&Kl[m1][e1] = pre1;
    }
    __syncthreads();
    if (c < 31) {
      pre0 = kg4[(c + 1) * 512 + tid];
      pre1 = kg4[(c + 1) * 512 + tid + 256];
    }
    float a0 = 0.f, a1 = 0.f, a2 = 0.f, a3 = 0.f;
#pragma unroll
    for (int i = 0; i < 8; ++i) {
      const float4 kv4 = *(const float4*)&Kl[lane][i * 4];
      a0 = fmaf(qv[0][i].x, kv4.x, a0); a0 = fmaf(qv[0][i].y, kv4.y, a0);
      a0 = fmaf(qv[0][i].z, kv4.z, a0); a0 = fmaf(qv[0][i].w, kv4.w, a0);
      a1 = fmaf(qv[1][i].x, kv4.x, a1); a1 = fmaf(qv[1][i].y, kv4.y, a1);
      a1 = fmaf(qv[1][i].z, kv4.z, a1); a1 = fmaf(qv[1][i].w, kv4.w, a1);
      a2 = fmaf(qv[2][i].x, kv4.x, a2); a2 = fmaf(qv[2][i].y, kv4.y, a2);
      a2 = fmaf(qv[2][i].z, kv4.z, a2); a2 = fmaf(qv[2][i].w, kv4.w, a2);
      a3 = fmaf(qv[3][i].x, kv4.x, a3); a3 = fmaf(qv[3][i].y, kv4.y, a3);
      a3 = fmaf(qv[3][i].z, kv4.z, a3); a3 = fmaf(qv[3][i].w, kv4.w, a3);
    }
    const float rs = 0.17677669529663687f;     // 1/sqrt(32)
    const int m = c * 64 + lane;
    Sc[(size_t)(wave * 4 + 0) * MMM + m] = a0 * rs;
    Sc[(size_t)(wave * 4 + 1) * MMM + m] = a1 * rs;
    Sc[(size_t)(wave * 4 + 2) * MMM + m] = a2 * rs;
    Sc[(size_t)(wave * 4 + 3) * MMM + m] = a3 * rs;
  }
  __syncthreads();

  // ---- phase 2: radix top-32 ----
  // A[r][i] (post-transpose): bit j = ordkey(s_r[j*64+lane]) bit (31-i)
  unsigned A[4][32];
#pragma unroll
  for (int r = 0; r < 4; ++r) {
    const float* sr = &Sc[(size_t)(wave * 4 + r) * MMM];
#pragma unroll
    for (int j = 0; j < 32; ++j)
      A[r][j] = ordkey(sr[(31 - j) * 64 + lane]);
    transpose32(A[r]);
  }

  unsigned act[4] = {~0u, ~0u, ~0u, ~0u};
  unsigned def[4] = {0u, 0u, 0u, 0u};
  unsigned tau[4] = {0u, 0u, 0u, 0u};
  int      Kq[4]  = {32, 32, 32, 32};

#pragma unroll
  for (int i = 0; i < 32; ++i) {           // MSB -> LSB (bit = 31-i)
    unsigned hh[4];
#pragma unroll
    for (int r = 0; r < 4; ++r) hh[r] = act[r] & A[r][i];
    int pkA = __builtin_popcount(hh[0]) | (__builtin_popcount(hh[1]) << 16);
    int pkB = __builtin_popcount(hh[2]) | (__builtin_popcount(hh[3]) << 16);
    pkA = dpp_scan_i32(pkA);
    pkB = dpp_scan_i32(pkB);
    const int sA = __builtin_amdgcn_readlane(pkA, 63);
    const int sB = __builtin_amdgcn_readlane(pkB, 63);
    const int c4[4] = { sA & 0xFFFF, (int)((unsigned)sA >> 16),
                        sB & 0xFFFF, (int)((unsigned)sB >> 16) };
#pragma unroll
    for (int r = 0; r < 4; ++r) {
      if (c4[r] >= Kq[r]) {                 // wave-uniform
        act[r] = hh[r];
        tau[r] |= 1u << (31 - i);
      } else {
        Kq[r] -= c4[r];
        def[r] |= hh[r];
        act[r] &= ~A[r][i];
      }
    }
  }

  // ---- per-row: tie fixup, softmax (tau-shifted), P*V ----
  float* scrP = (float*)&Kl[0][0] + wave * 64;   // 32 p + 32 m, per wave
  int*   scrM = (int*)(scrP + 32);
  const int e = lane & 31, half = lane >> 5;

#pragma unroll
  for (int r = 0; r < 4; ++r) {
    unsigned a_r = act[r];
    const int T = __builtin_amdgcn_readlane(
        dpp_scan_i32(__builtin_popcount(a_r)), 63);
    if (T != Kq[r]) {                       // rare exact-tie path (uniform)
      unsigned sact = 0u;
      int rem = Kq[r];
      for (int j = 0; j < 32 && rem > 0; ++j) {
        const unsigned long long bal = __ballot((a_r >> j) & 1u);
        const int cnt = __popcll(bal);
        const int take = cnt < rem ? cnt : rem;
        const unsigned long long below = bal & ((1ull << lane) - 1ull);
        if (((a_r >> j) & 1u) && (int)__popcll(below) < take)
          sact |= 1u << j;
        rem -= take;
      }
      a_r = sact;
    }
    const unsigned sel = def[r] | a_r;

    const unsigned tb = (tau[r] & 0x80000000u) ? (tau[r] & 0x7FFFFFFFu)
                                               : ~tau[r];
    const float tauf = __uint_as_float(tb);
    const float* srow = &Sc[(size_t)(wave * 4 + r) * MMM];

    const int ns = __builtin_popcount(sel);
    int pos = dpp_scan_i32(ns) - ns;        // exclusive offset
    asm volatile("s_waitcnt lgkmcnt(0)" ::: "memory");  // prev-row reads done
    unsigned mrem = sel;
    while (mrem) {
      const int j = __ffs(mrem) - 1; mrem &= mrem - 1;
      const int m = j * 64 + lane;
      scrP[pos] = __expf(srow[m] - tauf);
      scrM[pos] = m;
      ++pos;
    }
    asm volatile("s_waitcnt lgkmcnt(0)" ::: "memory");  // writes visible

    float ps = scrP[lane & 31];
    ps += __shfl_xor(ps, 1);  ps += __shfl_xor(ps, 2);
    ps += __shfl_xor(ps, 4);  ps += __shfl_xor(ps, 8);
    ps += __shfl_xor(ps, 16);
    const float rinv = 1.0f / ps;

    float accv = 0.f;
#pragma unroll
    for (int jj = 0; jj < 16; ++jj) {
      const int j2 = jj * 2 + half;
      const float pj = scrP[j2];
      const int   mj = scrM[j2];
      accv = fmaf(pj, vbase[(size_t)mj * DH + e], accv);
    }
    accv += __shfl_xor(accv, 32);
    accv *= rinv;
    if (lane < 32)
      msg[((size_t)b * DD + (e * HHH + h)) * NNN + (n0 + wave * 4 + r)] = accv;
  }
}

// ---------------------------------------------------------------- launch
extern "C" void kernel_launch(void* const* d_in, const int* in_sizes, int n_in,
                              void* d_out, int out_size, void* d_ws, size_t ws_size,
                              hipStream_t stream)
{
  const float* x   = (const float*)d_in[0];
  const float* src = (const float*)d_in[1];
  const float* Wq  = (const float*)d_in[2];
  const float* bq  = (const float*)d_in[3];
  const float* Wk  = (const float*)d_in[4];
  const float* bk  = (const float*)d_in[5];
  const float* Wv  = (const float*)d_in[6];
  const float* bv  = (const float*)d_in[7];
  const float* Wm  = (const float*)d_in[8];
  const float* bm  = (const float*)d_in[9];
  const float* W1  = (const float*)d_in[10];
  const float* b1  = (const float*)d_in[11];
  const float* g1  = (const float*)d_in[12];
  const float* be1 = (const float*)d_in[13];
  const float* mu1 = (const float*)d_in[14];
  const float* va1 = (const float*)d_in[15];
  const float* W2  = (const float*)d_in[16];
  const float* b2  = (const float*)d_in[17];

  float* ws = (float*)d_ws;
  const size_t SEG = 2097152;
  float* q_t  = ws;
  float* k_t  = ws + SEG;
  float* v_t  = ws + 2 * SEG;
  float* msg  = ws + 3 * SEG;
  float* msg2 = ws;
  float* z    = ws + SEG;

  const dim3 blk(256);
  const dim3 g128(256, 1), g256(256, 2);

  gemm_k<0><<<g128, blk, 0, stream>>>(Wq, bq, x,   nullptr, q_t, 128, 128,
                                      nullptr, nullptr, nullptr, nullptr);
  gemm_k<0><<<g128, blk, 0, stream>>>(Wk, bk, src, nullptr, k_t, 128, 128,
                                      nullptr, nullptr, nullptr, nullptr);
  gemm_k<0><<<g128, blk, 0, stream>>>(Wv, bv, src, nullptr, v_t, 128, 128,
                                      nullptr, nullptr, nullptr, nullptr);

  const size_t smem = (size_t)TN * MMM * 4 + 64 * 36 * 4;
  hipFuncSetAttribute(reinterpret_cast<const void*>(attn_k),
                      hipFuncAttributeMaxDynamicSharedMemorySize, (int)smem);
  const dim3 ga(NNN / TN, HHH, BB);
  attn_k<<<ga, blk, smem, stream>>>(q_t, k_t, v_t, msg);

  gemm_k<1><<<g128, blk, 0, stream>>>(Wm, bm, msg, nullptr, msg2, 128, 128,
                                      nullptr, nullptr, nullptr, nullptr);
  gemm_k<2><<<g256, blk, 0, stream>>>(W1, b1, x, msg2, z, 256, 256,
                                      g1, be1, mu1, va1);
  gemm_k<3><<<g128, blk, 0, stream>>>(W2, b2, z, nullptr, (float*)d_out, 256, 128,
                                      nullptr, nullptr, nullptr, nullptr);
}

// Round 3
// 437.039 us; speedup vs baseline: 6.1792x; 1.3715x over previous
//
#include <hip/hip_runtime.h>

#define BB   8
#define DD   128
#define HHH  4
#define NNN  2048
#define MMM  2048
#define DH   32
#define TN   8      // score rows per attention block (8 -> 78.8KB LDS -> 2 blocks/CU)
#define SCPAD 34    // lane stride in floats: 8B-aligned float2, 2-way bank on writes
#define SCROWS (64 * SCPAD)

// ---------------------------------------------------------------- GEMM
// MODE 0: qkv proj  -> out[b][h][n][e]  (c = e*4 + h head-split transpose)
// MODE 1: plain bias -> out[b][c][n]
// MODE 2: bias + BN + ReLU, input = concat(x, msg2) along channels
// MODE 3: bias       -> out[b][c][n]   (final delta)
template<int MODE>
__global__ __launch_bounds__(256)
void gemm_k(const float* __restrict__ W, const float* __restrict__ bias,
            const float* __restrict__ X0, const float* __restrict__ X1,
            float* __restrict__ out, int K, int Mrows,
            const float* __restrict__ g1, const float* __restrict__ be1,
            const float* __restrict__ mu1, const float* __restrict__ va1)
{
  __shared__ float Wt[32][132];
  __shared__ float Xl[32][64];
  const int tid = threadIdx.x;
  const int b   = blockIdx.x >> 5;
  const int n0  = (blockIdx.x & 31) << 6;
  const int rblk = blockIdx.y << 7;
  const int tx = tid & 15, ty = tid >> 4;

  float acc[8][4];
#pragma unroll
  for (int i = 0; i < 8; ++i)
#pragma unroll
    for (int j = 0; j < 4; ++j) acc[i][j] = 0.f;

  for (int k0 = 0; k0 < K; k0 += 32) {
#pragma unroll
    for (int i = 0; i < 4; ++i) {
      int idx = tid + i * 256;
      int r = idx >> 3, kv = (idx & 7) << 2;
      const float4 w4 = *(const float4*)&W[(size_t)(rblk + r) * K + k0 + kv];
      Wt[kv + 0][r] = w4.x; Wt[kv + 1][r] = w4.y;
      Wt[kv + 2][r] = w4.z; Wt[kv + 3][r] = w4.w;
    }
#pragma unroll
    for (int i = 0; i < 2; ++i) {
      int idx = tid + i * 256;
      int kk = idx >> 4, j4 = (idx & 15) << 2;
      int kg = k0 + kk;
      const float* src;
      if (MODE == 2)
        src = (kg < DD) ? &X0[((size_t)b * DD + kg) * NNN]
                        : &X1[((size_t)b * DD + (kg - DD)) * NNN];
      else
        src = &X0[((size_t)b * K + kg) * NNN];
      *(float4*)&Xl[kk][j4] = *(const float4*)&src[n0 + j4];
    }
    __syncthreads();
#pragma unroll
    for (int kk = 0; kk < 32; ++kk) {
      float a[8], bx[4];
      *(float4*)&a[0] = *(const float4*)&Wt[kk][ty * 8];
      *(float4*)&a[4] = *(const float4*)&Wt[kk][ty * 8 + 4];
      *(float4*)&bx[0] = *(const float4*)&Xl[kk][tx * 4];
#pragma unroll
      for (int i = 0; i < 8; ++i)
#pragma unroll
        for (int j = 0; j < 4; ++j) acc[i][j] = fmaf(a[i], bx[j], acc[i][j]);
    }
    __syncthreads();
  }

#pragma unroll
  for (int i = 0; i < 8; ++i) {
    const int r = rblk + ty * 8 + i;
    const float bv = bias[r];
    float scale = 1.f, shift = 0.f;
    if (MODE == 2) {
      const float inv = rsqrtf(va1[r] + 1e-5f);
      scale = g1[r] * inv;
      shift = be1[r] - mu1[r] * scale;
    }
#pragma unroll
    for (int j = 0; j < 4; ++j) {
      const int n = n0 + tx * 4 + j;
      float v = acc[i][j] + bv;
      if (MODE == 2) { v = fmaf(v, scale, shift); v = v > 0.f ? v : 0.f; }
      if (MODE == 0) {
        out[(((size_t)b * HHH + (r & 3)) * NNN + n) * DH + (r >> 2)] = v;
      } else {
        out[((size_t)b * Mrows + r) * NNN + n] = v;
      }
    }
  }
}

// ---------------------------------------------------------------- helpers
__device__ __forceinline__ int dpp_scan_i32(int v) {
  v += __builtin_amdgcn_update_dpp(0, v, 0x111, 0xF, 0xF, true); // row_shr:1
  v += __builtin_amdgcn_update_dpp(0, v, 0x112, 0xF, 0xF, true); // row_shr:2
  v += __builtin_amdgcn_update_dpp(0, v, 0x114, 0xF, 0xF, true); // row_shr:4
  v += __builtin_amdgcn_update_dpp(0, v, 0x118, 0xF, 0xF, true); // row_shr:8
  v += __builtin_amdgcn_update_dpp(0, v, 0x142, 0xA, 0xF, true); // row_bcast:15
  v += __builtin_amdgcn_update_dpp(0, v, 0x143, 0xC, 0xF, true); // row_bcast:31
  return v;
}

__device__ __forceinline__ unsigned ordkey(float f) {
  unsigned b = __float_as_uint(f);
  return (b & 0x80000000u) ? ~b : (b | 0x80000000u);
}

__device__ __forceinline__ void transpose32(unsigned (&A)[32]) {
  unsigned m = 0x0000FFFFu;
#pragma unroll
  for (int j = 16; j != 0; j = j >> 1, m = m ^ (m << j)) {
#pragma unroll
    for (int k = 0; k < 32; ++k) {
      if (!(k & j)) {
        unsigned t = (A[k] ^ (A[k + j] >> j)) & m;
        A[k]     ^= t;
        A[k + j] ^= t << j;
      }
    }
  }
}

// ---------------------------------------------------------------- attention
// 8 rows/block, 4 waves, 2 rows/wave. 78.8KB LDS -> 2 blocks/CU (2 waves/SIMD).
// Sc layout [row][lane][c] (pad 34): conflict-free b64 bitplane loads.
__global__ __launch_bounds__(256, 2)
void attn_k(const float* __restrict__ qt, const float* __restrict__ kt,
            const float* __restrict__ vt, float* __restrict__ msg)
{
  extern __shared__ char smem[];
  float* Sc = (float*)smem;                                  // [TN][64][SCPAD]
  float (*Kl)[36] = (float(*)[36])(smem + (size_t)TN * SCROWS * 4);

  const int tid  = threadIdx.x;
  const int wave = tid >> 6, lane = tid & 63;
  const int h = blockIdx.y, b = blockIdx.z;
  const int n0 = blockIdx.x * TN;
  const size_t bh = (size_t)b * HHH + h;
  const float* kbase = kt + bh * MMM * DH;
  const float* vbase = vt + bh * MMM * DH;
  const float* qbase = qt + (bh * NNN + n0) * DH;

  float4 qv[2][8];
#pragma unroll
  for (int r = 0; r < 2; ++r) {
    const float4* qr = (const float4*)(qbase + (size_t)(wave * 2 + r) * DH);
#pragma unroll
    for (int i = 0; i < 8; ++i) qv[r][i] = qr[i];
  }

  float* s0 = Sc + (size_t)(wave * 2 + 0) * SCROWS + lane * SCPAD;
  float* s1 = Sc + (size_t)(wave * 2 + 1) * SCROWS + lane * SCPAD;

  // ---- phase 1: scores (unscaled; order-preserving) ----
  const float4* kg4 = (const float4*)kbase;
  float4 pre0 = kg4[tid], pre1 = kg4[tid + 256];
  const int m0 = tid >> 3, e0 = (tid & 7) << 2;
  for (int c = 0; c < 32; ++c) {
    __syncthreads();                       // Kl free to overwrite
    *(float4*)&Kl[m0][e0]      = pre0;
    *(float4*)&Kl[m0 + 32][e0] = pre1;
    __syncthreads();
    if (c < 31) {
      pre0 = kg4[(c + 1) * 512 + tid];
      pre1 = kg4[(c + 1) * 512 + tid + 256];
    }
    float a0 = 0.f, a1 = 0.f;
#pragma unroll
    for (int i = 0; i < 8; ++i) {
      const float4 kv4 = *(const float4*)&Kl[lane][i * 4];
      a0 = fmaf(qv[0][i].x, kv4.x, a0); a0 = fmaf(qv[0][i].y, kv4.y, a0);
      a0 = fmaf(qv[0][i].z, kv4.z, a0); a0 = fmaf(qv[0][i].w, kv4.w, a0);
      a1 = fmaf(qv[1][i].x, kv4.x, a1); a1 = fmaf(qv[1][i].y, kv4.y, a1);
      a1 = fmaf(qv[1][i].z, kv4.z, a1); a1 = fmaf(qv[1][i].w, kv4.w, a1);
    }
    s0[c] = a0;                            // 2-way bank conflict: free
    s1[c] = a1;
  }
  __syncthreads();                         // all waves done with Kl (scratch reuse)

  // ---- phase 2: bitplanes + packed 2-row radix top-32 ----
  unsigned A[2][32];
#pragma unroll
  for (int r = 0; r < 2; ++r) {
    const float2* sp = (const float2*)((r == 0) ? s0 : s1);
#pragma unroll
    for (int i = 0; i < 16; ++i) {
      const float2 v = sp[i];              // elems c=2i, 2i+1
      A[r][31 - 2 * i]     = ordkey(v.x);
      A[r][31 - 2 * i - 1] = ordkey(v.y);
    }
    transpose32(A[r]);
  }

  unsigned act[2] = {~0u, ~0u}, def[2] = {0u, 0u}, tau[2] = {0u, 0u};
  int Kq[2] = {32, 32}, rem[2] = {MMM, MMM};
  bool done0 = false, done1 = false;

#pragma unroll
  for (int i = 0; i < 32; ++i) {           // MSB -> LSB, early break on exact fill
    const unsigned h0 = act[0] & A[0][i];
    const unsigned h1 = act[1] & A[1][i];
    int pk = __builtin_popcount(h0) | (__builtin_popcount(h1) << 16);
    pk = dpp_scan_i32(pk);
    const int s = __builtin_amdgcn_readlane(pk, 63);
    const int c0 = s & 0xFFFF, c1 = (int)((unsigned)s >> 16);
    if (!done0) {
      if (c0 >= Kq[0]) { act[0] = h0; tau[0] |= 1u << (31 - i); rem[0] = c0; }
      else { Kq[0] -= c0; def[0] |= h0; act[0] &= ~A[0][i]; rem[0] -= c0; }
      done0 = (rem[0] == Kq[0]);
    }
    if (!done1) {
      if (c1 >= Kq[1]) { act[1] = h1; tau[1] |= 1u << (31 - i); rem[1] = c1; }
      else { Kq[1] -= c1; def[1] |= h1; act[1] &= ~A[1][i]; rem[1] -= c1; }
      done1 = (rem[1] == Kq[1]);
    }
    if (done0 && done1) break;
  }

  // ---- per-row: tie fixup (rare), softmax (tau-shifted), P*V ----
  float* scrP = (float*)&Kl[0][0] + wave * 64;   // 32 p + 32 m per wave
  int*   scrM = (int*)(scrP + 32);
  const int e = lane & 31, half = lane >> 5;
  const float rs = 0.17677669529663687f;         // 1/sqrt(32)

#pragma unroll
  for (int r = 0; r < 2; ++r) {
    unsigned a_r = act[r];
    const bool done_r = (r == 0) ? done0 : done1;
    if (!done_r) {                         // ties: index-order fixup (uniform)
      unsigned sact = 0u;
      int remq = Kq[r];
      for (int j = 0; j < 32 && remq > 0; ++j) {
        const unsigned long long bal = __ballot((a_r >> j) & 1u);
        const int cnt = __popcll(bal);
        const int take = cnt < remq ? cnt : remq;
        const unsigned long long below = bal & ((1ull << lane) - 1ull);
        if (((a_r >> j) & 1u) && (int)__popcll(below) < take)
          sact |= 1u << j;
        remq -= take;
      }
      a_r = sact;
    }
    const unsigned sel = def[r] | a_r;

    const unsigned tb = (tau[r] & 0x80000000u) ? (tau[r] & 0x7FFFFFFFu)
                                               : ~tau[r];
    const float tauf = __uint_as_float(tb);
    const float* srow = (r == 0) ? s0 : s1;

    const int ns = __builtin_popcount(sel);
    int pos = dpp_scan_i32(ns) - ns;       // exclusive offset
    asm volatile("s_waitcnt lgkmcnt(0)" ::: "memory");
    unsigned mrem = sel;
    while (mrem) {
      const int j = __ffs(mrem) - 1; mrem &= mrem - 1;
      scrP[pos] = __expf((srow[j] - tauf) * rs);
      scrM[pos] = j * 64 + lane;
      ++pos;
    }
    asm volatile("s_waitcnt lgkmcnt(0)" ::: "memory");

    float ps = scrP[lane & 31];
    ps += __shfl_xor(ps, 1);  ps += __shfl_xor(ps, 2);
    ps += __shfl_xor(ps, 4);  ps += __shfl_xor(ps, 8);
    ps += __shfl_xor(ps, 16);
    const float rinv = 1.0f / ps;

    float accv = 0.f;
#pragma unroll
    for (int jj = 0; jj < 16; ++jj) {
      const int j2 = jj * 2 + half;
      const float pj = scrP[j2];
      const int   mj = scrM[j2];
      accv = fmaf(pj, vbase[(size_t)mj * DH + e], accv);
    }
    accv += __shfl_xor(accv, 32);
    accv *= rinv;
    if (lane < 32)
      msg[((size_t)b * DD + (e * HHH + h)) * NNN + (n0 + wave * 2 + r)] = accv;
  }
}

// ---------------------------------------------------------------- launch
extern "C" void kernel_launch(void* const* d_in, const int* in_sizes, int n_in,
                              void* d_out, int out_size, void* d_ws, size_t ws_size,
                              hipStream_t stream)
{
  const float* x   = (const float*)d_in[0];
  const float* src = (const float*)d_in[1];
  const float* Wq  = (const float*)d_in[2];
  const float* bq  = (const float*)d_in[3];
  const float* Wk  = (const float*)d_in[4];
  const float* bk  = (const float*)d_in[5];
  const float* Wv  = (const float*)d_in[6];
  const float* bv  = (const float*)d_in[7];
  const float* Wm  = (const float*)d_in[8];
  const float* bm  = (const float*)d_in[9];
  const float* W1  = (const float*)d_in[10];
  const float* b1  = (const float*)d_in[11];
  const float* g1  = (const float*)d_in[12];
  const float* be1 = (const float*)d_in[13];
  const float* mu1 = (const float*)d_in[14];
  const float* va1 = (const float*)d_in[15];
  const float* W2  = (const float*)d_in[16];
  const float* b2  = (const float*)d_in[17];

  float* ws = (float*)d_ws;
  const size_t SEG = 2097152;
  float* q_t  = ws;
  float* k_t  = ws + SEG;
  float* v_t  = ws + 2 * SEG;
  float* msg  = ws + 3 * SEG;
  float* msg2 = ws;
  float* z    = ws + SEG;

  const dim3 blk(256);
  const dim3 g128(256, 1), g256(256, 2);

  gemm_k<0><<<g128, blk, 0, stream>>>(Wq, bq, x,   nullptr, q_t, 128, 128,
                                      nullptr, nullptr, nullptr, nullptr);
  gemm_k<0><<<g128, blk, 0, stream>>>(Wk, bk, src, nullptr, k_t, 128, 128,
                                      nullptr, nullptr, nullptr, nullptr);
  gemm_k<0><<<g128, blk, 0, stream>>>(Wv, bv, src, nullptr, v_t, 128, 128,
                                      nullptr, nullptr, nullptr, nullptr);

  const size_t smem = (size_t)TN * SCROWS * 4 + 64 * 36 * 4;   // 78848 B
  hipFuncSetAttribute(reinterpret_cast<const void*>(attn_k),
                      hipFuncAttributeMaxDynamicSharedMemorySize, (int)smem);
  const dim3 ga(NNN / TN, HHH, BB);
  attn_k<<<ga, blk, smem, stream>>>(q_t, k_t, v_t, msg);

  gemm_k<1><<<g128, blk, 0, stream>>>(Wm, bm, msg, nullptr, msg2, 128, 128,
                                      nullptr, nullptr, nullptr, nullptr);
  gemm_k<2><<<g256, blk, 0, stream>>>(W1, b1, x, msg2, z, 256, 256,
                                      g1, be1, mu1, va1);
  gemm_k<3><<<g128, blk, 0, stream>>>(W2, b2, z, nullptr, (float*)d_out, 256, 128,
                                      nullptr, nullptr, nullptr, nullptr);
}